// Round 7
// baseline (200.897 us; speedup 1.0000x reference)
//
#include <hip/hip_runtime.h>

// BagOfWords: input [1024, 512] int32 tokens in [0, 50257).
// Output [1024, 50256] float32: per-row histogram, vocab bin 0 dropped.
//
// R10: persistent half-row + mask-gated zero-constant streaming.
//
// Ledger (kernel-side us, = dur - 123 poison fill - ~20 dispatch): R0
// fused=55, R2 persistent=52, R5 mask=52, R6 wide@4blk/CU=57. Mechanism
// synthesis:
//  - End-of-dispatch release forces vmcnt(0) before s_endpgm -> short-lived
//    blocks (13312) eat ~52 exposed store-drains per CU + 13x token
//    refetch. The 6.7 TB/s rocclr fill runs ONE huge store run per wave,
//    one drain, at 10% occupancy.
//  - R2 (persistent, 1 drain/block) still drained per-chunk: its store data
//    regs (hreg) were overwritten by the next chunk's ds_read -> compiler
//    vmcnt(0) (WAR on store SOURCE regs).
//  - R5's mask trick makes the common-path store data a constant-zero reg
//    that is NEVER overwritten -> no WAR. Address-reg recycling costs only
//    partial vmcnt(N) waits -- the fill kernel itself does that.
//  - R6: 16 waves/CU cannot cover the serial phases; keep 8 blocks/CU.
// This kernel: 2048 half-row blocks, 20 KB LDS (8/CU, 32 waves), per block
// {1 token load, 6-7 chunks x [LDS atomics+mask, lgkm bar, mask-gated
// stores (zero-burst + rare sparse), masked re-zero, lgkm bar], 1 drain}.
// Plain stores, NOT nontemporal (R4: nt bypasses MALL absorption, +10 us).

#define BATCH 1024
#define SEQ 512
#define VOCAB 50257
#define OUT_COLS (VOCAB - 1)   // 50256
#define CHUNK 4096
#define NGROUP (CHUNK / 4)     // 1024 groups of 4 bins
#define NCHUNK 13              // 12 full + 1104-col tail
#define BLOCK 256

// LDS-only barrier: waits ds ops (lgkmcnt) but does NOT drain global stores
// (__syncthreads would emit s_waitcnt vmcnt(0) and stall the store pipe).
#define LDS_BAR()                                              \
    do {                                                       \
        asm volatile("s_waitcnt lgkmcnt(0)" ::: "memory");     \
        __builtin_amdgcn_s_barrier();                          \
        asm volatile("" ::: "memory");                         \
    } while (0)

__global__ __launch_bounds__(BLOCK) void bow_rowhalf_kernel(
    const int* __restrict__ tokens, float* __restrict__ out) {
    __shared__ unsigned int hist[CHUNK];   // 16 KB
    __shared__ unsigned int mask[NGROUP];  // 4 KB

    const int t = threadIdx.x;
    const int b = blockIdx.x >> 1;        // row
    const int h = blockIdx.x & 1;         // chunk-range half
    const int cbeg = h ? 7 : 0;
    const int cend = h ? NCHUNK : 7;

    // Row tokens once, int2/thread, live across all chunks.
    const int2 tk = ((const int2*)(tokens + (size_t)b * SEQ))[t];
    const unsigned int cx = (unsigned int)(tk.x - 1);  // tok==0 -> 0xFFFFFFFF
    const unsigned int cy = (unsigned int)(tk.y - 1);

    const uint4 z4 = make_uint4(0u, 0u, 0u, 0u);
    #pragma unroll
    for (int k = 0; k < 4; ++k)
        *(uint4*)&hist[t * 4 + k * (BLOCK * 4)] = z4;
    *(uint4*)&mask[t * 4] = z4;

    LDS_BAR();

    for (int c = cbeg; c < cend; ++c) {
        const unsigned int c0 = (unsigned int)c * CHUNK;

        // Histogram + mark occupied 4-bin groups (all mask writes are 1u;
        // races benign). tok==0 dropped via unsigned underflow.
        unsigned int r;
        r = cx - c0;
        if (r < CHUNK) { atomicAdd(&hist[r], 1u); mask[r >> 2] = 1u; }
        r = cy - c0;
        if (r < CHUNK) { atomicAdd(&hist[r], 1u); mask[r >> 2] = 1u; }

        LDS_BAR();

        float* obase = out + (size_t)b * OUT_COLS + c0;
        const int ncols = (c0 + CHUNK <= (unsigned)OUT_COLS)
                              ? CHUNK : (OUT_COLS - (int)c0);  // tail: 1104

        // Thread t owns groups {t, t+256, t+512, t+768}; batch 4 mask reads
        // (one lgkm wait). Stores at 4*group are lane-contiguous per k.
        unsigned int m[4];
        #pragma unroll
        for (int k = 0; k < 4; ++k)
            m[k] = mask[t + k * BLOCK];

        // Zero-burst: constant-zero data reg, never overwritten -> no WAR,
        // stores pipeline back-to-back across chunks.
        const float4 zf = make_float4(0.f, 0.f, 0.f, 0.f);
        #pragma unroll
        for (int k = 0; k < 4; ++k) {
            const int base = t * 4 + k * (BLOCK * 4);
            if (base < ncols && m[k] == 0u)
                *(float4*)(obase + base) = zf;
        }

        // Sparse pass (~40 groups/block/chunk): LDS read + cvt + store,
        // then re-zero own hist group + mask word (owner == storer; per-wave
        // LDS ordering keeps read-before-write). Disjoint addrs from burst.
        // Max token bin = 50255 < OUT_COLS, so masked groups are always
        // inside ncols.
        #pragma unroll
        for (int k = 0; k < 4; ++k) {
            const int base = t * 4 + k * (BLOCK * 4);
            if (base < ncols && m[k] != 0u) {
                const uint4 hh = *(const uint4*)&hist[base];
                *(float4*)(obase + base) = make_float4(
                    (float)hh.x, (float)hh.y, (float)hh.z, (float)hh.w);
                *(uint4*)&hist[base] = z4;
                mask[t + k * BLOCK] = 0u;
            }
        }

        LDS_BAR();  // re-zeros visible before next chunk's atomics
    }
}

extern "C" void kernel_launch(void* const* d_in, const int* in_sizes, int n_in,
                              void* d_out, int out_size, void* d_ws, size_t ws_size,
                              hipStream_t stream) {
    const int* tokens = (const int*)d_in[0];
    float* out = (float*)d_out;

    bow_rowhalf_kernel<<<dim3(BATCH * 2), dim3(BLOCK), 0, stream>>>(tokens, out);
}